// Round 2
// baseline (318.967 us; speedup 1.0000x reference)
//
#include <hip/hip_runtime.h>

// Problem constants (reference: DIM=64, WIRES=3, INDEX=1, BATCH=128)
#define DIMQ   64
#define NCOLS  8192            // right * batch = 64*128
#define SLAB   (DIMQ * NCOLS)  // per-a complex elements = 524288
#define NA     64              // left = dim^index
#define DB     (NA * SLAB)     // D*B = 33554432

#define NT     128             // n-columns per tile
#define TILES  8               // tiles per persistent block
#define NCG    8               // column groups: 8192 / (TILES*NT) per a-slab

typedef __attribute__((ext_vector_type(8))) __bf16 bf16x8;
typedef __attribute__((ext_vector_type(8))) unsigned short us8;
typedef __attribute__((ext_vector_type(4))) unsigned short us4;
typedef __attribute__((ext_vector_type(4))) float f32x4;

__device__ __forceinline__ unsigned short f2bf(float f) {
    unsigned u = __builtin_bit_cast(unsigned, f);
    unsigned r = u + 0x7fffu + ((u >> 16) & 1u);   // RNE to bf16
    return (unsigned short)(r >> 16);
}

// X-tile LDS swizzle: logical bf16 tile [n=128][k=64], pitch 64 u16 (128 B).
// 16B chunk index (k>>3) is XOR-swizzled with row bits so that BOTH the
// transpose writes (rows 4i+z per lane, fixed chunk) and the fragment reads
// (rows l15, chunk q) spread uniformly (8 lanes per 16B chunk = b128/b64 min).
__device__ __forceinline__ int xsw(int row, int chunk) {
    return chunk ^ ((row >> 2) & 7) ^ ((row & 3) << 1);
}

// ---- Variant A: output = Re(y) only, out_size = D*B float32 ----
// Persistent 512-thread blocks (8 waves), 2 blocks/CU, grid 64a x 8cg.
// Each block processes 8 tiles (64 k x 128 n); loads for tile t+1 are issued
// before the barriers of tile t so HBM traffic flows across compute phases.
__global__ __launch_bounds__(512, 4) void gate_real_kernel(
    const float* __restrict__ Mr, const float* __restrict__ Mi,
    const float* __restrict__ Xr, const float* __restrict__ Xi,
    float* __restrict__ Out)
{
    // LDS 32 KB: Xr bf16 tile (16 KB) + Xi bf16 tile (16 KB); the fp32 output
    // stage (64 x 128 f32 = 32 KB) reuses the whole region after a barrier.
    __shared__ alignas(16) unsigned char smem[32768];
    unsigned short* ldsX = (unsigned short*)smem;   // R at elem 0, I at 8192
    float* ldsO = (float*)smem;

    const int tid  = threadIdx.x;
    const int lane = tid & 63;
    const int w    = tid >> 6;        // wave 0..7
    const int l15  = lane & 15;
    const int q    = lane >> 4;
    const int it   = w & 3;           // i-tile (16 rows of M)
    const int nh   = w >> 2;          // n-half (64 cols)

    const int a  = blockIdx.x >> 3;
    const int cg = blockIdx.x & 7;
    const size_t baseA = (size_t)a * SLAB;
    const int ncg0 = cg * (TILES * NT);

    // --- M fragments for this wave's i-tile. Negate Mi once so
    //     accR = Mr (x) Xr + (-Mi) (x) Xi needs no X-side negation. ---
    bf16x8 fMr[2], fMni[2];
#pragma unroll
    for (int kb = 0; kb < 2; ++kb) {
        const int row = it * 16 + l15;
        const int col = kb * 32 + q * 8;
        const float* pr = Mr + row * DIMQ + col;
        const float* pi = Mi + row * DIMQ + col;
        us8 hr, hni;
#pragma unroll
        for (int j = 0; j < 8; ++j) {
            hr[j]  = f2bf(pr[j]);
            hni[j] = (unsigned short)(f2bf(pi[j]) ^ 0x8000u);
        }
        fMr[kb]  = __builtin_bit_cast(bf16x8, hr);
        fMni[kb] = __builtin_bit_cast(bf16x8, hni);
    }

    // Staging geometry: thread owns 4 k-rows x 4 n-cols.
    const int k0    = (tid >> 5) * 4;     // 0..60
    const int sn    = (tid & 31) * 4;     // 0..124
    const int chunk = k0 >> 3;
    const int ko4   = k0 & 4;

    // --- prologue: load tile 0 into registers (coalesced dwordx4) ---
    f32x4 vr[4], vi[4];
    {
        const float* gr = Xr + baseA + (size_t)k0 * NCOLS + ncg0 + sn;
        const float* gi = Xi + baseA + (size_t)k0 * NCOLS + ncg0 + sn;
#pragma unroll
        for (int j = 0; j < 4; ++j)
            vr[j] = *reinterpret_cast<const f32x4*>(gr + (size_t)j * NCOLS);
#pragma unroll
        for (int j = 0; j < 4; ++j)
            vi[j] = *reinterpret_cast<const f32x4*>(gi + (size_t)j * NCOLS);
    }

    for (int t = 0; t < TILES; ++t) {
        // --- convert regs -> swizzled bf16 LDS tile (transpose in regs) ---
#pragma unroll
        for (int z = 0; z < 4; ++z) {
            const int row = sn + z;
            const int e   = row * 64 + xsw(row, chunk) * 8 + ko4;
            us4 hr, hi;
#pragma unroll
            for (int j = 0; j < 4; ++j) {
                hr[j] = f2bf(vr[j][z]);
                hi[j] = f2bf(vi[j][z]);
            }
            *reinterpret_cast<us4*>(&ldsX[e])        = hr;
            *reinterpret_cast<us4*>(&ldsX[8192 + e]) = hi;
        }

        // --- issue next tile's global loads; they stay in flight across the
        //     barriers / MFMA / epilogue below (T14 async-stage split) ---
        if (t + 1 < TILES) {
            const float* gr = Xr + baseA + (size_t)k0 * NCOLS + ncg0 + (t + 1) * NT + sn;
            const float* gi = Xi + baseA + (size_t)k0 * NCOLS + ncg0 + (t + 1) * NT + sn;
#pragma unroll
            for (int j = 0; j < 4; ++j)
                vr[j] = *reinterpret_cast<const f32x4*>(gr + (size_t)j * NCOLS);
#pragma unroll
            for (int j = 0; j < 4; ++j)
                vi[j] = *reinterpret_cast<const f32x4*>(gi + (size_t)j * NCOLS);
        }
        __syncthreads();

        // --- MFMA: wave computes i-tile `it` x 64 cols (n-half `nh`) ---
        f32x4 acc[4];
#pragma unroll
        for (int nt = 0; nt < 4; ++nt) acc[nt] = f32x4{0, 0, 0, 0};
#pragma unroll
        for (int nt = 0; nt < 4; ++nt) {
#pragma unroll
            for (int kb = 0; kb < 2; ++kb) {
                const int row = (nh * 4 + nt) * 16 + l15;
                const int e   = row * 64 + xsw(row, kb * 4 + q) * 8;
                const bf16x8 bXr = __builtin_bit_cast(bf16x8,
                    *reinterpret_cast<const us8*>(&ldsX[e]));
                const bf16x8 bXi = __builtin_bit_cast(bf16x8,
                    *reinterpret_cast<const us8*>(&ldsX[8192 + e]));
                acc[nt] = __builtin_amdgcn_mfma_f32_16x16x32_bf16(fMr[kb],  bXr, acc[nt], 0, 0, 0);
                acc[nt] = __builtin_amdgcn_mfma_f32_16x16x32_bf16(fMni[kb], bXi, acc[nt], 0, 0, 0);
            }
        }
        __syncthreads();   // X-tile reads done -> LDS reused for output stage

        // --- acc -> swizzled fp32 out stage. C/D layout: col=l15, row=q*4+r.
        //     dword swizzle d' = col ^ ((row&7)<<2): 2 lanes/bank on writes,
        //     conflict-free 16B-contiguous reads. ---
#pragma unroll
        for (int nt = 0; nt < 4; ++nt) {
#pragma unroll
            for (int r = 0; r < 4; ++r) {
                const int row = it * 16 + q * 4 + r;
                const int col = nh * 64 + nt * 16 + l15;
                ldsO[row * 128 + (col ^ ((row & 7) << 2))] = acc[nt][r];
            }
        }
        __syncthreads();

        // --- coalesced dwordx4 stores: each half-wave stores a 512 B row ---
        {
            const int ci = (tid & 31) * 4;
            const int r0 = tid >> 5;          // 0..15
            const int n0 = ncg0 + t * NT;
#pragma unroll
            for (int p = 0; p < 4; ++p) {
                const int row = p * 16 + r0;
                const int d   = ci ^ ((row & 7) << 2);
                const f32x4 v = *reinterpret_cast<const f32x4*>(&ldsO[row * 128 + d]);
                *reinterpret_cast<f32x4*>(Out + baseA + (size_t)row * NCOLS + n0 + ci) = v;
            }
        }
        __syncthreads();   // out-stage reads done before next X-tile write
    }
}

// ---- Variant B (fallback): interleaved complex64 view, out_size = 2*D*B ----
// Kept as the previously-verified implementation.
__device__ __forceinline__ void load_M_frags_full(
    const float* __restrict__ Mr, const float* __restrict__ Mi,
    int l15, int q, bf16x8 fMr[4][2], bf16x8 fMi[4][2])
{
#pragma unroll
    for (int it = 0; it < 4; ++it) {
#pragma unroll
        for (int kb = 0; kb < 2; ++kb) {
            const int row = it * 16 + l15;
            const int col = kb * 32 + q * 8;
            const float* pr = Mr + row * DIMQ + col;
            const float* pi = Mi + row * DIMQ + col;
            us8 hr, hi;
#pragma unroll
            for (int j = 0; j < 8; ++j) {
                hr[j] = f2bf(pr[j]);
                hi[j] = f2bf(pi[j]);
            }
            fMr[it][kb] = __builtin_bit_cast(bf16x8, hr);
            fMi[it][kb] = __builtin_bit_cast(bf16x8, hi);
        }
    }
}

__global__ __launch_bounds__(64, 2) void gate_cplx_kernel(
    const float* __restrict__ Mr, const float* __restrict__ Mi,
    const float* __restrict__ Xr, const float* __restrict__ Xi,
    float* __restrict__ Out)
{
    const int lane = threadIdx.x;
    const int l15  = lane & 15;
    const int q    = lane >> 4;

    bf16x8 fMr[4][2], fMi[4][2];
    load_M_frags_full(Mr, Mi, l15, q, fMr, fMi);

    const int bid = blockIdx.x;
    const int a   = bid >> 6;
    const int nch = bid & 63;
    const size_t baseA = (size_t)a * SLAB;

    for (int tt = 0; tt < 8; ++tt) {
        const int n0 = nch * 128 + tt * 16;
        f32x4 accR[4] = {f32x4{0,0,0,0}, f32x4{0,0,0,0}, f32x4{0,0,0,0}, f32x4{0,0,0,0}};
        f32x4 accI[4] = {f32x4{0,0,0,0}, f32x4{0,0,0,0}, f32x4{0,0,0,0}, f32x4{0,0,0,0}};

#pragma unroll
        for (int kb = 0; kb < 2; ++kb) {
            const int krow = kb * 32 + q * 8;
            const float* pr = Xr + baseA + (size_t)krow * NCOLS + n0 + l15;
            const float* pi = Xi + baseA + (size_t)krow * NCOLS + n0 + l15;
            float fr[8], fi[8];
#pragma unroll
            for (int j = 0; j < 8; ++j) {
                fr[j] = pr[(size_t)j * NCOLS];
                fi[j] = pi[(size_t)j * NCOLS];
            }
            us8 hr, hi, hni;
#pragma unroll
            for (int j = 0; j < 8; ++j) {
                hr[j] = f2bf(fr[j]);
                const unsigned short tbf = f2bf(fi[j]);
                hi[j]  = tbf;
                hni[j] = (unsigned short)(tbf ^ 0x8000u);
            }
            const bf16x8 bXr  = __builtin_bit_cast(bf16x8, hr);
            const bf16x8 bXi  = __builtin_bit_cast(bf16x8, hi);
            const bf16x8 bXni = __builtin_bit_cast(bf16x8, hni);

#pragma unroll
            for (int it = 0; it < 4; ++it) {
                accR[it] = __builtin_amdgcn_mfma_f32_16x16x32_bf16(fMr[it][kb], bXr,  accR[it], 0, 0, 0);
                accR[it] = __builtin_amdgcn_mfma_f32_16x16x32_bf16(fMi[it][kb], bXni, accR[it], 0, 0, 0);
                accI[it] = __builtin_amdgcn_mfma_f32_16x16x32_bf16(fMr[it][kb], bXi,  accI[it], 0, 0, 0);
                accI[it] = __builtin_amdgcn_mfma_f32_16x16x32_bf16(fMi[it][kb], bXr,  accI[it], 0, 0, 0);
            }
        }

#pragma unroll
        for (int it = 0; it < 4; ++it) {
#pragma unroll
            for (int r = 0; r < 4; ++r) {
                const int i = it * 16 + q * 4 + r;
                const size_t cidx = baseA + (size_t)i * NCOLS + n0 + l15;
                float2 v;
                v.x = accR[it][r];
                v.y = accI[it][r];
                reinterpret_cast<float2*>(Out)[cidx] = v;
            }
        }
    }
}

extern "C" void kernel_launch(void* const* d_in, const int* in_sizes, int n_in,
                              void* d_out, int out_size, void* d_ws, size_t ws_size,
                              hipStream_t stream) {
    const float* Mr = (const float*)d_in[0];
    const float* Mi = (const float*)d_in[1];
    const float* Xr = (const float*)d_in[2];
    const float* Xi = (const float*)d_in[3];
    float* Out = (float*)d_out;

    if (out_size >= 2 * DB) {
        dim3 grid(NA * 64);
        dim3 block(64);
        gate_cplx_kernel<<<grid, block, 0, stream>>>(Mr, Mi, Xr, Xi, Out);
    } else {
        dim3 grid(NA * NCG);   // 64 a-slabs * 8 column groups (persistent, 8 tiles each)
        dim3 block(512);
        gate_real_kernel<<<grid, block, 0, stream>>>(Mr, Mi, Xr, Xi, Out);
    }
}

// Round 4
// 316.767 us; speedup vs baseline: 1.0069x; 1.0069x over previous
//
#include <hip/hip_runtime.h>

// Problem constants (reference: DIM=64, WIRES=3, INDEX=1, BATCH=128)
#define DIMQ   64
#define NCOLS  8192            // right * batch = 64*128
#define SLAB   (DIMQ * NCOLS)  // per-a complex elements = 524288
#define NA     64              // left = dim^index
#define DB     (NA * SLAB)     // D*B = 33554432

#define NT     64              // n-columns per tile
#define TILES  8               // tiles per block
#define NCG    16              // column groups per a-slab: 16*8*64 = 8192

typedef __attribute__((ext_vector_type(8))) __bf16 bf16x8;
typedef __attribute__((ext_vector_type(8))) unsigned short us8;
typedef __attribute__((ext_vector_type(4))) unsigned short us4;
typedef __attribute__((ext_vector_type(4))) float f32x4;

__device__ __forceinline__ unsigned short f2bf(float f) {
    unsigned u = __builtin_bit_cast(unsigned, f);
    unsigned r = u + 0x7fffu + ((u >> 16) & 1u);   // RNE to bf16
    return (unsigned short)(r >> 16);
}

// X-tile swizzle: logical bf16 tile [n=64 rows][k=64], pitch 64 u16 (128 B).
// The 16B chunk index (k>>3) is XORed with row bits so both the transpose
// writes and the fragment reads hit banks uniformly (b64/b128 minimum).
__device__ __forceinline__ int xsw(int row, int chunk) {
    return chunk ^ ((row >> 2) & 7) ^ ((row & 3) << 1);
}

// Raw barrier: LDS visibility only (lgkmcnt). Does NOT drain vmcnt, so
// prefetched global loads stay in flight across it (the round-2 failure was
// __syncthreads() draining vmcnt(0) at every barrier).
#define BARRIER() do { \
    asm volatile("s_waitcnt lgkmcnt(0)" ::: "memory"); \
    __builtin_amdgcn_s_barrier(); \
} while (0)

// ---- Variant A: output = Re(y) only, out_size = D*B float32 ----
// 512-thread blocks, 8 tiles of 64k x 64n each. X tiles double-buffered in
// LDS; tile t+1's global loads issued before tile t's barriers and consumed
// one tile later (true async overlap). 48 KB LDS -> up to 3 blocks/CU.
__global__ __launch_bounds__(512, 4) void gate_real_kernel(
    const float* __restrict__ Mr, const float* __restrict__ Mi,
    const float* __restrict__ Xr, const float* __restrict__ Xi,
    float* __restrict__ Out)
{
    __shared__ alignas(16) unsigned short ldsX[2][2][64 * 64]; // [buf][comp][n][k] 32 KB
    __shared__ alignas(16) float ldsO[64 * 64];                // [i][n] swizzled, 16 KB

    const int tid  = threadIdx.x;
    const int lane = tid & 63;
    const int w    = tid >> 6;        // wave 0..7
    const int l15  = lane & 15;
    const int q    = lane >> 4;
    const int it   = w & 3;           // i-tile (16 rows of M)
    const int nh   = (w >> 2) & 1;    // n-half (32 cols)

    const int a  = blockIdx.x >> 4;   // 64 a-slabs
    const int cg = blockIdx.x & 15;   // 16 column groups
    const size_t baseA = (size_t)a * SLAB;
    const int ncg0 = cg * (TILES * NT);

    // --- M fragments for this wave's i-tile. Negate Mi once so
    //     accR = Mr (x) Xr + (-Mi) (x) Xi needs no X-side negation. ---
    bf16x8 fMr[2], fMni[2];
#pragma unroll
    for (int kb = 0; kb < 2; ++kb) {
        const int row = it * 16 + l15;
        const int col = kb * 32 + q * 8;
        const float* pr = Mr + row * DIMQ + col;
        const float* pi = Mi + row * DIMQ + col;
        us8 hr, hni;
#pragma unroll
        for (int j = 0; j < 8; ++j) {
            hr[j]  = f2bf(pr[j]);
            hni[j] = (unsigned short)(f2bf(pi[j]) ^ 0x8000u);
        }
        fMr[kb]  = __builtin_bit_cast(bf16x8, hr);
        fMni[kb] = __builtin_bit_cast(bf16x8, hni);
    }

    // Staging geometry: threads 0..255 stage Re, 256..511 stage Im.
    // Each thread: 4 consecutive k-rows x 4 consecutive n-cols.
    const int c  = tid >> 8;                 // component
    const int k0 = ((tid >> 4) & 15) * 4;    // 0..60
    const int sn = (tid & 15) * 4;           // 0..60
    const float* Xc = c ? Xi : Xr;
    const float* gbase = Xc + baseA + (size_t)k0 * NCOLS + ncg0 + sn;

    f32x4 vA[4], vB[4];

    auto LOADT = [&](f32x4 v[4], int t) {
        const float* g = gbase + (size_t)t * NT;
#pragma unroll
        for (int j = 0; j < 4; ++j)
            v[j] = *reinterpret_cast<const f32x4*>(g + (size_t)j * NCOLS);
    };

    auto XWRITE = [&](const f32x4 v[4], int buf) {
        unsigned short* L = &ldsX[buf][c][0];
        const int chunk = k0 >> 3;
        const int ko4   = k0 & 4;
#pragma unroll
        for (int z = 0; z < 4; ++z) {
            const int row = sn + z;
            const int e   = row * 64 + xsw(row, chunk) * 8 + ko4;
            us4 h;
#pragma unroll
            for (int j = 0; j < 4; ++j) h[j] = f2bf(v[j][z]);
            *reinterpret_cast<us4*>(&L[e]) = h;
        }
    };

    auto COMPUTE = [&](int buf, f32x4 acc[2]) {
        acc[0] = f32x4{0, 0, 0, 0};
        acc[1] = f32x4{0, 0, 0, 0};
#pragma unroll
        for (int nt = 0; nt < 2; ++nt) {
#pragma unroll
            for (int kb = 0; kb < 2; ++kb) {
                const int row = nh * 32 + nt * 16 + l15;
                const int e   = row * 64 + xsw(row, kb * 4 + q) * 8;
                const bf16x8 bXr = __builtin_bit_cast(bf16x8,
                    *reinterpret_cast<const us8*>(&ldsX[buf][0][e]));
                const bf16x8 bXi = __builtin_bit_cast(bf16x8,
                    *reinterpret_cast<const us8*>(&ldsX[buf][1][e]));
                acc[nt] = __builtin_amdgcn_mfma_f32_16x16x32_bf16(fMr[kb],  bXr, acc[nt], 0, 0, 0);
                acc[nt] = __builtin_amdgcn_mfma_f32_16x16x32_bf16(fMni[kb], bXi, acc[nt], 0, 0, 0);
            }
        }
    };

    // C/D layout: col = l15, row = q*4 + r. Dword swizzle col ^ ((row&7)<<2):
    // writes 2 lanes/bank (free), reads 8/bank (b128 minimum).
    auto OWRITE = [&](const f32x4 acc[2]) {
#pragma unroll
        for (int nt = 0; nt < 2; ++nt) {
#pragma unroll
            for (int r = 0; r < 4; ++r) {
                const int row = it * 16 + q * 4 + r;
                const int col = nh * 32 + nt * 16 + l15;
                ldsO[row * 64 + (col ^ ((row & 7) << 2))] = acc[nt][r];
            }
        }
    };

    auto OSTORE = [&](int t) {
        const int ci = (tid & 15) * 4;
        const int r0 = tid >> 4;          // 0..31
        const int n0 = ncg0 + t * NT;
#pragma unroll
        for (int p = 0; p < 2; ++p) {
            const int row = p * 32 + r0;
            const int d   = ci ^ ((row & 7) << 2);
            const f32x4 v = *reinterpret_cast<const f32x4*>(&ldsO[row * 64 + d]);
            *reinterpret_cast<f32x4*>(Out + baseA + (size_t)row * NCOLS + n0 + ci) = v;
        }
    };

    f32x4 acc[2];

    // --- prologue: tile 0 (regs A, buf 0) ---
    LOADT(vA, 0);
    XWRITE(vA, 0);          // vmcnt wait folds in at first f2bf use
    LOADT(vB, 1);           // tile 1 in flight across the barriers below
    BARRIER();
    COMPUTE(0, acc);
    OWRITE(acc);
    BARRIER();

    // --- steady state: tiles 1..6 in odd/even pairs (static reg indexing) ---
    for (int t = 1; t < TILES - 1; t += 2) {
        // tile t: regs B, buf 1
        OSTORE(t - 1);
        XWRITE(vB, 1);
        LOADT(vA, t + 1);
        BARRIER();
        COMPUTE(1, acc);
        OWRITE(acc);
        BARRIER();
        // tile t+1: regs A, buf 0
        OSTORE(t);
        XWRITE(vA, 0);
        if (t + 2 < TILES) LOADT(vB, t + 2);
        BARRIER();
        COMPUTE(0, acc);
        OWRITE(acc);
        BARRIER();
    }

    // --- epilogue: tile 7 (regs B, buf 1) ---
    OSTORE(TILES - 2);
    XWRITE(vB, 1);
    BARRIER();
    COMPUTE(1, acc);
    OWRITE(acc);
    BARRIER();
    OSTORE(TILES - 1);
}

// ---- Variant B (fallback): interleaved complex64 view, out_size = 2*D*B ----
// Kept as the previously-verified implementation.
__device__ __forceinline__ void load_M_frags_full(
    const float* __restrict__ Mr, const float* __restrict__ Mi,
    int l15, int q, bf16x8 fMr[4][2], bf16x8 fMi[4][2])
{
#pragma unroll
    for (int it = 0; it < 4; ++it) {
#pragma unroll
        for (int kb = 0; kb < 2; ++kb) {
            const int row = it * 16 + l15;
            const int col = kb * 32 + q * 8;
            const float* pr = Mr + row * DIMQ + col;
            const float* pi = Mi + row * DIMQ + col;
            us8 hr, hi;
#pragma unroll
            for (int j = 0; j < 8; ++j) {
                hr[j] = f2bf(pr[j]);
                hi[j] = f2bf(pi[j]);
            }
            fMr[it][kb] = __builtin_bit_cast(bf16x8, hr);
            fMi[it][kb] = __builtin_bit_cast(bf16x8, hi);
        }
    }
}

__global__ __launch_bounds__(64, 2) void gate_cplx_kernel(
    const float* __restrict__ Mr, const float* __restrict__ Mi,
    const float* __restrict__ Xr, const float* __restrict__ Xi,
    float* __restrict__ Out)
{
    const int lane = threadIdx.x;
    const int l15  = lane & 15;
    const int q    = lane >> 4;

    bf16x8 fMr[4][2], fMi[4][2];
    load_M_frags_full(Mr, Mi, l15, q, fMr, fMi);

    const int bid = blockIdx.x;
    const int a   = bid >> 6;
    const int nch = bid & 63;
    const size_t baseA = (size_t)a * SLAB;

    for (int tt = 0; tt < 8; ++tt) {
        const int n0 = nch * 128 + tt * 16;
        f32x4 accR[4] = {f32x4{0,0,0,0}, f32x4{0,0,0,0}, f32x4{0,0,0,0}, f32x4{0,0,0,0}};
        f32x4 accI[4] = {f32x4{0,0,0,0}, f32x4{0,0,0,0}, f32x4{0,0,0,0}, f32x4{0,0,0,0}};

#pragma unroll
        for (int kb = 0; kb < 2; ++kb) {
            const int krow = kb * 32 + q * 8;
            const float* pr = Xr + baseA + (size_t)krow * NCOLS + n0 + l15;
            const float* pi = Xi + baseA + (size_t)krow * NCOLS + n0 + l15;
            float fr[8], fi[8];
#pragma unroll
            for (int j = 0; j < 8; ++j) {
                fr[j] = pr[(size_t)j * NCOLS];
                fi[j] = pi[(size_t)j * NCOLS];
            }
            us8 hr, hi, hni;
#pragma unroll
            for (int j = 0; j < 8; ++j) {
                hr[j] = f2bf(fr[j]);
                const unsigned short tbf = f2bf(fi[j]);
                hi[j]  = tbf;
                hni[j] = (unsigned short)(tbf ^ 0x8000u);
            }
            const bf16x8 bXr  = __builtin_bit_cast(bf16x8, hr);
            const bf16x8 bXi  = __builtin_bit_cast(bf16x8, hi);
            const bf16x8 bXni = __builtin_bit_cast(bf16x8, hni);

#pragma unroll
            for (int it = 0; it < 4; ++it) {
                accR[it] = __builtin_amdgcn_mfma_f32_16x16x32_bf16(fMr[it][kb], bXr,  accR[it], 0, 0, 0);
                accR[it] = __builtin_amdgcn_mfma_f32_16x16x32_bf16(fMi[it][kb], bXni, accR[it], 0, 0, 0);
                accI[it] = __builtin_amdgcn_mfma_f32_16x16x32_bf16(fMr[it][kb], bXi,  accI[it], 0, 0, 0);
                accI[it] = __builtin_amdgcn_mfma_f32_16x16x32_bf16(fMi[it][kb], bXr,  accI[it], 0, 0, 0);
            }
        }

#pragma unroll
        for (int it = 0; it < 4; ++it) {
#pragma unroll
            for (int r = 0; r < 4; ++r) {
                const int i = it * 16 + q * 4 + r;
                const size_t cidx = baseA + (size_t)i * NCOLS + n0 + l15;
                float2 v;
                v.x = accR[it][r];
                v.y = accI[it][r];
                reinterpret_cast<float2*>(Out)[cidx] = v;
            }
        }
    }
}

extern "C" void kernel_launch(void* const* d_in, const int* in_sizes, int n_in,
                              void* d_out, int out_size, void* d_ws, size_t ws_size,
                              hipStream_t stream) {
    const float* Mr = (const float*)d_in[0];
    const float* Mi = (const float*)d_in[1];
    const float* Xr = (const float*)d_in[2];
    const float* Xi = (const float*)d_in[3];
    float* Out = (float*)d_out;

    if (out_size >= 2 * DB) {
        dim3 grid(NA * 64);
        dim3 block(64);
        gate_cplx_kernel<<<grid, block, 0, stream>>>(Mr, Mi, Xr, Xi, Out);
    } else {
        dim3 grid(NA * NCG);   // 64 a-slabs * 16 column groups, 8 tiles each
        dim3 block(512);
        gate_real_kernel<<<grid, block, 0, stream>>>(Mr, Mi, Xr, Xi, Out);
    }
}